// Round 22
// baseline (132.475 us; speedup 1.0000x reference)
//
#include <hip/hip_runtime.h>

// Problem constants
#define BB 16
#define CC 128
#define MM 32
#define NN 16384   // H*W

// Workspace layout (float offsets)
#define WS_KV     0        // [16][32][32]
#define WS_KS     16384    // [16][32]
#define WS_SQ     16896    // [16][32]
#define WS_QQ     17408    // [16][32][32]
#define WS_YSUM   33792    // [128]
#define WS_YSQ    33920    // [128]
#define WS_ACCEND 34048    // zeroed region end
#define WS_W2     34304    // [16][128][32]
#define WS_WPACK  99840    // bf16[2][3][32][128] (hi then lo) = 49152 B

typedef __bf16 bf16x8 __attribute__((ext_vector_type(8)));
typedef __bf16 bf16x4 __attribute__((ext_vector_type(4)));
typedef float  f32x16 __attribute__((ext_vector_type(16)));

union B8 { bf16x8 v8; bf16x4 v4[2]; };

__device__ __forceinline__ float phi_f(float z) {
    return z > 0.f ? z + 1.f : __expf(z);
}

// Raw barrier with LDS-only drain (global ops stay in flight).
__device__ __forceinline__ void lds_barrier() {
    asm volatile("s_waitcnt lgkmcnt(0)" ::: "memory");
    __builtin_amdgcn_sched_barrier(0);
    __builtin_amdgcn_s_barrier();
    __builtin_amdgcn_sched_barrier(0);
}

// ---------------------------------------------------------------------------
__global__ void zero_kernel(float* ws) {
    const int i = blockIdx.x * 256 + threadIdx.x;
    if (i < (WS_ACCEND / 4)) {
        float4 z; z.x = 0.f; z.y = 0.f; z.z = 0.f; z.w = 0.f;
        ((float4*)ws)[i] = z;
    }
}

// ---------------------------------------------------------------------------
// Pack Wq/Wk/Wv rows into bf16 hi/lo fragment buffer (one-time, tiny).
// Layout: hi at [mi*4096 + m*128 + k], lo at +12288 (bf16 indices).
__global__ void wpack_kernel(const float* __restrict__ Wq,
                             const float* __restrict__ Wk,
                             const float* __restrict__ Wv, float* ws) {
    __bf16* wp = (__bf16*)(ws + WS_WPACK);
    const int idx = blockIdx.x * 256 + threadIdx.x;   // 0..12287
    if (idx < 12288) {
        const int mi  = idx >> 12;
        const int rem = idx & 4095;
        const float f = (mi == 0 ? Wq : mi == 1 ? Wk : Wv)[rem];
        const __bf16 h = (__bf16)f;
        wp[idx]         = h;
        wp[12288 + idx] = (__bf16)(f - (float)h);
    }
}

// ---------------------------------------------------------------------------
// ROUND-22: single-round proj blocks (qq-proven geometry).
// grid (256,16) x 256 threads; each block = ONE 64-px tile, one pass:
//   stage X hi-only -> bar -> waves 0-2 proj MFMA (2-term W-exact split:
//   Wx ~= Wh*Xh + Wl*Xh) + Q->global / K,V->LDS -> bar -> ALL 4 waves KV/Ks
//   MFMA (one 16-px k-slice each) -> bar -> LDS reduce -> atomics.
// LDS 35.8 KB -> 4 blocks/CU. W-frags loaded from the packed bf16 buffer
// (16 vector loads vs 128 scalar: this was the per-block overhead that made
// small blocks lose in r6/r15).
__global__ __launch_bounds__(256) void projmfma_kernel(
    const float* __restrict__ x, const float* ws_c,
    float* ws, float* __restrict__ qout)
{
    __shared__ __align__(16) char smem[35840];
    __bf16* Xh  = (__bf16*)smem;                    // [64][136] = 17408 B
    __bf16* ktH = (__bf16*)(smem + 17408);          // [32][72] = 4608 B
    __bf16* ktL = (__bf16*)(smem + 22016);
    __bf16* vtH = (__bf16*)(smem + 26624);
    __bf16* vtL = (__bf16*)(smem + 31232);
    float*  red   = (float*)smem;                   // [256*17] overlay on Xh
    float*  ksred = (float*)(smem + 17408);         // [128] overlay on ktH

    const int b = blockIdx.y;
    const int t = threadIdx.x;
    const int w = t >> 6;
    const int l = t & 63;
    const int g = l >> 5;
    const int ln31 = l & 31;

    const int n0 = blockIdx.x << 6;

    // ---- W fragments from packed buffer (waves 0..2): 16 vector loads
    bf16x8 wh[8], wl[8];
    if (w < 3) {
        const __bf16* wp = (const __bf16*)(ws_c + WS_WPACK) + w * 4096 + ln31 * 128;
        #pragma unroll
        for (int kt = 0; kt < 8; ++kt) {
            wh[kt] = *(const bf16x8*)&wp[16 * kt + 8 * g];
            wl[kt] = *(const bf16x8*)&wp[12288 + 16 * kt + 8 * g];
        }
    }

    // ---- stage 64-px X tile (hi only): thread t -> px t&63, 32 channels
    {
        const int px = t & 63;
        const int cb = t >> 6;    // 0..3
        const float* xp = x + (size_t)b * CC * NN + n0 + px;
        float xb[32];
        #pragma unroll
        for (int j = 0; j < 32; ++j)
            xb[j] = xp[(size_t)(cb * 32 + j) * NN];
        __bf16 hb[32];
        #pragma unroll
        for (int j = 0; j < 32; ++j) hb[j] = (__bf16)xb[j];
        #pragma unroll
        for (int q = 0; q < 4; ++q)
            *(bf16x8*)&Xh[px * 136 + cb * 32 + q * 8] = *(bf16x8*)&hb[q * 8];
    }
    lds_barrier();

    // ---- phase 1: proj MFMA (waves 0-2), write Q / K / V
    if (w < 3) {
        f32x16 a0, a1;
        #pragma unroll
        for (int i = 0; i < 16; ++i) { a0[i] = 0.f; a1[i] = 0.f; }
        #pragma unroll
        for (int kt = 0; kt < 8; ++kt) {
            const int k0 = 16 * kt + 8 * g;
            const bf16x8 b0 = *(const bf16x8*)&Xh[ln31 * 136 + k0];
            const bf16x8 b1 = *(const bf16x8*)&Xh[(ln31 + 32) * 136 + k0];
            a0 = __builtin_amdgcn_mfma_f32_32x32x16_bf16(wh[kt], b0, a0, 0, 0, 0);
            a0 = __builtin_amdgcn_mfma_f32_32x32x16_bf16(wl[kt], b0, a0, 0, 0, 0);
            a1 = __builtin_amdgcn_mfma_f32_32x32x16_bf16(wh[kt], b1, a1, 0, 0, 0);
            a1 = __builtin_amdgcn_mfma_f32_32x32x16_bf16(wl[kt], b1, a1, 0, 0, 0);
        }
        if (w == 0) {
            float* qp = qout + (size_t)b * CC * NN + n0 + ln31;
            #pragma unroll
            for (int i = 0; i < 16; ++i) {
                const int r = (i & 3) + 8 * (i >> 2) + 4 * g;
                qp[(size_t)r * NN]      = phi_f(a0[i]);
                qp[(size_t)r * NN + 32] = phi_f(a1[i]);
            }
        } else if (w == 1) {
            #pragma unroll
            for (int i = 0; i < 16; ++i) {
                const int r = (i & 3) + 8 * (i >> 2) + 4 * g;
                const float f0 = phi_f(a0[i]);
                const float f1 = phi_f(a1[i]);
                const __bf16 h0 = (__bf16)f0;
                const __bf16 h1 = (__bf16)f1;
                ktH[r * 72 + ln31]      = h0;
                ktL[r * 72 + ln31]      = (__bf16)(f0 - (float)h0);
                ktH[r * 72 + 32 + ln31] = h1;
                ktL[r * 72 + 32 + ln31] = (__bf16)(f1 - (float)h1);
            }
        } else {
            #pragma unroll
            for (int i = 0; i < 16; ++i) {
                const int r = (i & 3) + 8 * (i >> 2) + 4 * g;
                const float f0 = a0[i];
                const float f1 = a1[i];
                const __bf16 h0 = (__bf16)f0;
                const __bf16 h1 = (__bf16)f1;
                vtH[r * 72 + ln31]      = h0;
                vtL[r * 72 + ln31]      = (__bf16)(f0 - (float)h0);
                vtH[r * 72 + 32 + ln31] = h1;
                vtL[r * 72 + 32 + ln31] = (__bf16)(f1 - (float)h1);
            }
        }
    }
    lds_barrier();

    // ---- phase 2: ALL waves KV/Ks MFMA, wave w takes k-slice [16w, 16w+16)
    f32x16 kvA, ksA;
    bf16x8 ones;
    #pragma unroll
    for (int i = 0; i < 16; ++i) { kvA[i] = 0.f; ksA[i] = 0.f; }
    #pragma unroll
    for (int j = 0; j < 8; ++j) ones[j] = (__bf16)1.0f;
    {
        const int k0 = 16 * w + 8 * g;
        const bf16x8 akh = *(const bf16x8*)&ktH[ln31 * 72 + k0];
        const bf16x8 akl = *(const bf16x8*)&ktL[ln31 * 72 + k0];
        const bf16x8 bvh = *(const bf16x8*)&vtH[ln31 * 72 + k0];
        const bf16x8 bvl = *(const bf16x8*)&vtL[ln31 * 72 + k0];
        kvA = __builtin_amdgcn_mfma_f32_32x32x16_bf16(akh, bvh, kvA, 0, 0, 0);
        kvA = __builtin_amdgcn_mfma_f32_32x32x16_bf16(akh, bvl, kvA, 0, 0, 0);
        kvA = __builtin_amdgcn_mfma_f32_32x32x16_bf16(akl, bvh, kvA, 0, 0, 0);
        ksA = __builtin_amdgcn_mfma_f32_32x32x16_bf16(akh, ones, ksA, 0, 0, 0);
        ksA = __builtin_amdgcn_mfma_f32_32x32x16_bf16(akl, ones, ksA, 0, 0, 0);
    }
    lds_barrier();   // all Xh/kt/vt reads done before overlays

    // ---- cross-wave reduce (red overlays Xh, ksred overlays ktH)
    #pragma unroll
    for (int i = 0; i < 16; ++i) red[t * 17 + i] = kvA[i];
    if (ln31 == 0) {
        #pragma unroll
        for (int i = 0; i < 16; ++i) {
            const int r = (i & 3) + 8 * (i >> 2) + 4 * g;
            ksred[(w << 5) + r] = ksA[i];
        }
    }
    lds_barrier();
    if (t < 64) {
        float* kvb = ws + WS_KV + (b << 10);
        #pragma unroll
        for (int i = 0; i < 16; ++i) {
            const int r = (i & 3) + 8 * (i >> 2) + 4 * g;
            const float s = red[t*17+i] + red[(t+64)*17+i] + red[(t+128)*17+i] + red[(t+192)*17+i];
            atomicAdd(&kvb[r * 32 + ln31], s);
        }
    }
    if (t < 32) {
        const float s = ksred[t] + ksred[32 + t] + ksred[64 + t] + ksred[96 + t];
        atomicAdd(&ws[WS_KS + (b << 5) + t], s);
    }
}

// ---------------------------------------------------------------------------
// Pass C via MFMA (unchanged).  grid (64,16) x 256.
__global__ __launch_bounds__(256) void qq_kernel(const float* qsrc, float* ws) {
    __shared__ __align__(16) char qsm[33792];
    __bf16* Qh = (__bf16*)qsm;              // [32][264]
    __bf16* Ql = (__bf16*)(qsm + 16896);    // [32][264]
    float*  red   = (float*)qsm;
    float*  sqred = (float*)(qsm + 17408);

    const int b = blockIdx.y;
    const int t = threadIdx.x;
    const int w = t >> 6;
    const int l = t & 63;
    const int g = l >> 5;
    const int ln31 = l & 31;

    const float* ksb = ws + WS_KS + (b << 5);
    const int n = (blockIdx.x << 8) + t;
    const float* qp = qsrc + (size_t)b * CC * NN + n;

    float qa[32];
    #pragma unroll
    for (int m = 0; m < 32; ++m) qa[m] = qp[(size_t)m * NN];

    float denom = 1e-6f;
    #pragma unroll
    for (int m = 0; m < 32; ++m) denom = fmaf(qa[m], ksb[m], denom);
    const float inv = 1.0f / (16384.0f * denom);
    #pragma unroll
    for (int m = 0; m < 32; ++m) qa[m] *= inv;

    #pragma unroll
    for (int m = 0; m < 32; ++m) {
        const __bf16 h = (__bf16)qa[m];
        Qh[m * 264 + t] = h;
        Ql[m * 264 + t] = (__bf16)(qa[m] - (float)h);
    }
    __syncthreads();

    f32x16 qqA, sqA;
    bf16x8 ones;
    #pragma unroll
    for (int i = 0; i < 16; ++i) { qqA[i] = 0.f; sqA[i] = 0.f; }
    #pragma unroll
    for (int j = 0; j < 8; ++j) ones[j] = (__bf16)1.0f;

    #pragma unroll
    for (int sub = 0; sub < 2; ++sub) {
        #pragma unroll
        for (int s = 0; s < 2; ++s) {
            const int k0 = (w << 6) + (sub << 5) + s * 16 + g * 8;
            const bf16x8 ah = *(const bf16x8*)&Qh[ln31 * 264 + k0];
            const bf16x8 al = *(const bf16x8*)&Ql[ln31 * 264 + k0];
            qqA = __builtin_amdgcn_mfma_f32_32x32x16_bf16(ah, ah, qqA, 0, 0, 0);
            qqA = __builtin_amdgcn_mfma_f32_32x32x16_bf16(ah, al, qqA, 0, 0, 0);
            qqA = __builtin_amdgcn_mfma_f32_32x32x16_bf16(al, ah, qqA, 0, 0, 0);
            sqA = __builtin_amdgcn_mfma_f32_32x32x16_bf16(ah, ones, sqA, 0, 0, 0);
            sqA = __builtin_amdgcn_mfma_f32_32x32x16_bf16(al, ones, sqA, 0, 0, 0);
        }
    }
    __syncthreads();

    #pragma unroll
    for (int i = 0; i < 16; ++i) red[t * 17 + i] = qqA[i];
    if (ln31 == 0) {
        #pragma unroll
        for (int i = 0; i < 16; ++i) {
            const int r = (i & 3) + 8 * (i >> 2) + 4 * g;
            sqred[(w << 5) + r] = sqA[i];
        }
    }
    __syncthreads();
    if (t < 64) {
        float* qqb = ws + WS_QQ + (b << 10);
        #pragma unroll
        for (int i = 0; i < 16; ++i) {
            const int r = (i & 3) + 8 * (i >> 2) + 4 * g;
            const float s = red[t*17+i] + red[(t+64)*17+i] + red[(t+128)*17+i] + red[(t+192)*17+i];
            atomicAdd(&qqb[r * 32 + ln31], s);
        }
    }
    if (t < 32) {
        const float s = sqred[t] + sqred[32 + t] + sqred[64 + t] + sqred[96 + t];
        atomicAdd(&ws[WS_SQ + (b << 5) + t], s);
    }
}

// ---------------------------------------------------------------------------
// Merged W2 + BN stats (unchanged).
__global__ __launch_bounds__(128) void bnstat_kernel(const float* __restrict__ Wout,
                                                     float* ws) {
    const int b = blockIdx.x;
    const int c = threadIdx.x;
    const float* kvb = ws + WS_KV + (b << 10);
    const float* wo  = Wout + (c << 5);
    float w[32];
    #pragma unroll
    for (int v = 0; v < 32; ++v) w[v] = 0.f;
    for (int m = 0; m < 32; ++m) {
        const float wm = wo[m];
        #pragma unroll
        for (int v = 0; v < 32; ++v) w[v] = fmaf(wm, kvb[(m << 5) + v], w[v]);
    }
    float* w2b = ws + WS_W2 + (b << 12) + (c << 5);
    #pragma unroll
    for (int v = 0; v < 32; ++v) w2b[v] = w[v];

    const float* sq = ws + WS_SQ + (b << 5);
    const float* qq = ws + WS_QQ + (b << 10);
    float mb = 0.f;
    #pragma unroll
    for (int v = 0; v < 32; ++v) mb = fmaf(w[v], sq[v], mb);
    float qf = 0.f;
    for (int u = 0; u < 32; ++u) {
        float tacc = 0.f;
        #pragma unroll
        for (int v = 0; v < 32; ++v) tacc = fmaf(qq[(u << 5) + v], w[v], tacc);
        qf = fmaf(w[u], tacc, qf);
    }
    atomicAdd(&ws[WS_YSUM + c], mb);
    atomicAdd(&ws[WS_YSQ + c], qf);
}

// ---------------------------------------------------------------------------
// Output via MFMA with inline BN finalize (unchanged).
__global__ __launch_bounds__(256) void out_kernel(const float* qsrc, const float* ws,
                                                  const float* __restrict__ gamma,
                                                  const float* __restrict__ beta,
                                                  float* out) {
    __shared__ __align__(16) __bf16 Qh[256 * 36];
    __shared__ __align__(16) __bf16 Ql[256 * 36];
    __shared__ float scs[CC];
    __shared__ float bis[CC];

    const int b = blockIdx.y;
    const int t = threadIdx.x;
    const int w = t >> 6;
    const int l = t & 63;
    const int g = l >> 5;
    const int ln31 = l & 31;

    if (t < CC) {
        const float invBN = 1.0f / 262144.0f;
        const float mean = ws[WS_YSUM + t] * invBN;
        const float var  = ws[WS_YSQ + t] * invBN - mean * mean;
        const float s = gamma[t] * rsqrtf(var + 1e-5f);
        scs[t] = s;
        bis[t] = fmaf(-mean, s, beta[t]);
    }

    const int n = (blockIdx.x << 8) + t;
    const float* ksb = ws + WS_KS + (b << 5);

    const float* qp = qsrc + (size_t)b * CC * NN + n;
    float qa[32];
    #pragma unroll
    for (int m = 0; m < 32; ++m) qa[m] = qp[(size_t)m * NN];

    float d0 = 1e-6f;
    #pragma unroll
    for (int m = 0; m < 32; ++m) d0 = fmaf(qa[m], ksb[m], d0);
    const float inv = 1.0f / (16384.0f * d0);
    #pragma unroll
    for (int m = 0; m < 32; ++m) qa[m] *= inv;

    {
        __bf16 qh[32], ql[32];
        #pragma unroll
        for (int m = 0; m < 32; ++m) {
            const __bf16 h = (__bf16)qa[m];
            qh[m] = h;
            ql[m] = (__bf16)(qa[m] - (float)h);
        }
        #pragma unroll
        for (int i = 0; i < 8; ++i) {
            *(bf16x4*)&Qh[t * 36 + i * 4] = *(bf16x4*)&qh[i * 4];
            *(bf16x4*)&Ql[t * 36 + i * 4] = *(bf16x4*)&ql[i * 4];
        }
    }
    __syncthreads();

    const float* w2b = ws + WS_W2 + (b << 12);
    float* ob = out + (size_t)b * CC * NN + (blockIdx.x << 8);

    #pragma unroll
    for (int cb = 0; cb < 4; ++cb) {
        bf16x8 ah[2], al[2];
        #pragma unroll
        for (int kt = 0; kt < 2; ++kt) {
            const float* wp = w2b + (cb * 32 + ln31) * 32 + kt * 16 + g * 8;
            #pragma unroll
            for (int j = 0; j < 8; ++j) {
                const float f = wp[j];
                const __bf16 h = (__bf16)f;
                ah[kt][j] = h;
                al[kt][j] = (__bf16)(f - (float)h);
            }
        }
        #pragma unroll
        for (int pg = 0; pg < 2; ++pg) {
            const int px0 = (w << 6) + (pg << 5);
            f32x16 acc;
            #pragma unroll
            for (int i = 0; i < 16; ++i) acc[i] = 0.f;
            #pragma unroll
            for (int kt = 0; kt < 2; ++kt) {
                const int k0 = kt * 16 + g * 8;
                const __bf16* qhp = &Qh[(px0 + ln31) * 36 + k0];
                const __bf16* qlp = &Ql[(px0 + ln31) * 36 + k0];
                B8 bh, bl;
                bh.v4[0] = *(const bf16x4*)&qhp[0];
                bh.v4[1] = *(const bf16x4*)&qhp[4];
                bl.v4[0] = *(const bf16x4*)&qlp[0];
                bl.v4[1] = *(const bf16x4*)&qlp[4];
                acc = __builtin_amdgcn_mfma_f32_32x32x16_bf16(ah[kt], bh.v8, acc, 0, 0, 0);
                acc = __builtin_amdgcn_mfma_f32_32x32x16_bf16(ah[kt], bl.v8, acc, 0, 0, 0);
                acc = __builtin_amdgcn_mfma_f32_32x32x16_bf16(al[kt], bh.v8, acc, 0, 0, 0);
            }
            #pragma unroll
            for (int i = 0; i < 16; ++i) {
                const int r = (i & 3) + 8 * (i >> 2) + 4 * g;
                const int c = cb * 32 + r;
                const float v = fmaf(scs[c], acc[i], bis[c]);
                __builtin_nontemporal_store(v, &ob[(size_t)c * NN + px0 + ln31]);
            }
        }
    }
}

// ---------------------------------------------------------------------------
extern "C" void kernel_launch(void* const* d_in, const int* in_sizes, int n_in,
                              void* d_out, int out_size, void* d_ws, size_t ws_size,
                              hipStream_t stream) {
    const float* x     = (const float*)d_in[0];
    const float* Wq    = (const float*)d_in[1];
    const float* Wk    = (const float*)d_in[2];
    const float* Wv    = (const float*)d_in[3];
    const float* Wout  = (const float*)d_in[4];
    const float* gamma = (const float*)d_in[5];
    const float* beta  = (const float*)d_in[6];
    float* ws  = (float*)d_ws;
    float* out = (float*)d_out;

    zero_kernel<<<34, 256, 0, stream>>>(ws);
    wpack_kernel<<<48, 256, 0, stream>>>(Wq, Wk, Wv, ws);
    projmfma_kernel<<<dim3(256, 16), 256, 0, stream>>>(x, ws, ws, out);
    qq_kernel<<<dim3(64, 16), 256, 0, stream>>>(out, ws);
    bnstat_kernel<<<16, 128, 0, stream>>>(Wout, ws);
    out_kernel<<<dim3(64, 16), 256, 0, stream>>>(out, ws, gamma, beta, out);
}